// Round 17
// baseline (452.057 us; speedup 1.0000x reference)
//
#include <hip/hip_runtime.h>
#include <hip/hip_bf16.h>
#include <math.h>

typedef __hip_bfloat16 bf16;
typedef short bf16x8 __attribute__((ext_vector_type(8)));
typedef float floatx4 __attribute__((ext_vector_type(4)));

#define NTOK 841          // 29*29 patches
#define BATCH 8
#define DIM 256
#define HEADS 8
#define DH 32
#define IMG 457
#define HPAD 464
#define ROWS (BATCH * NTOK)   // 6728
#define LDA 40                // padded LDS row stride (bf16 elems) -> 80B

// weight segment offsets (elements) in the packed bf16 weight buffer
#define W_SPT   0
#define W_QKV   327680
#define W_OUT   917504
#define W_FF1   1114112
#define W_FF2   1900544
#define W_PIX   2686976
#define W_TOTAL 2752512

// ---------------------------------------------------------------------------
// Convert all weight tensors fp32 -> bf16 into one packed buffer.
// ---------------------------------------------------------------------------
__global__ __launch_bounds__(256) void wconv_kernel(
    const float* __restrict__ s_spt, const float* __restrict__ s_qkv,
    const float* __restrict__ s_out, const float* __restrict__ s_ff1,
    const float* __restrict__ s_ff2, const float* __restrict__ s_pix,
    bf16* __restrict__ dst) {
    int idx = (blockIdx.x * 256 + threadIdx.x) * 4;
    const float* src; int off;
    if      (idx < W_QKV) { src = s_spt; off = W_SPT; }
    else if (idx < W_OUT) { src = s_qkv; off = W_QKV; }
    else if (idx < W_FF1) { src = s_out; off = W_OUT; }
    else if (idx < W_FF2) { src = s_ff1; off = W_FF1; }
    else if (idx < W_PIX) { src = s_ff2; off = W_FF2; }
    else                  { src = s_pix; off = W_PIX; }
    float4 v = *(const float4*)(src + (idx - off));
    union { ushort4 u; bf16 h[4]; } pk;
    pk.h[0] = __float2bfloat16(v.x);
    pk.h[1] = __float2bfloat16(v.y);
    pk.h[2] = __float2bfloat16(v.z);
    pk.h[3] = __float2bfloat16(v.w);
    *(ushort4*)(dst + idx) = pk.u;
}

// ---------------------------------------------------------------------------
// Tokenize gather -> bf16 tok[ROWS][1280], k=(c,py,px).  (R6 proven)
// ---------------------------------------------------------------------------
__global__ __launch_bounds__(256) void tokenize_kernel(const float* __restrict__ x,
                                                       bf16* __restrict__ tok) {
    int idx = blockIdx.x * 256 + threadIdx.x;
    int gm = idx / 320;
    int k4 = (idx - gm * 320) * 4;
    int b = gm / NTOK;
    int n = gm - b * NTOK;
    int hp = n / 29, wp = n - (n / 29) * 29;
    int c = k4 >> 8;
    int py = (k4 >> 4) & 15;
    int px0 = k4 & 15;
    const int dxs[5] = {0, -8, 8, -8, 8};
    const int dys[5] = {0, -8, -8, 8, 8};
    int r = hp * 16 + py - dys[c];
    r += (r < 0) ? HPAD : 0; r -= (r >= HPAD) ? HPAD : 0;
    bool rok = (r < IMG);
    union { ushort4 u; bf16 h[4]; } pk;
#pragma unroll
    for (int i = 0; i < 4; i++) {
        int s = wp * 16 + px0 + i - dxs[c];
        s += (s < 0) ? HPAD : 0; s -= (s >= HPAD) ? HPAD : 0;
        float v = 0.0f;
        if (rok && s < IMG) v = x[((size_t)b * IMG + r) * IMG + s];
        pk.h[i] = __float2bfloat16(v);
    }
    *(ushort4*)(tok + (size_t)gm * 1280 + k4) = pk.u;
}

// ---------------------------------------------------------------------------
// Double-buffered MFMA GEMM (R16 proven): C = A@W^T, BK=32, 4 waves (2x2).
// Supports BM=32 (guarded staging). act: 0 none, 1 gelu, 2 pix-scatter.
// NOTE (R14): BM=32 only for N=256 GEMMs; wide-N GEMMs use BM=64 and gain
// grid occupancy by shrinking BN (R16: 64x64 QKV/FF1 = -81 us).
// ---------------------------------------------------------------------------
template <int BM, int BN>
__global__ __launch_bounds__(256) void gemm_db_kernel(
    const bf16* __restrict__ A, const bf16* __restrict__ W,
    const float* __restrict__ bias, const float* __restrict__ resid,
    const float* __restrict__ posemb, float* __restrict__ Cf,
    bf16* __restrict__ Cb, int M, int N, int K, int act) {
    constexpr int WM = BM / 2, WN = BN / 2;
    constexpr int TI = WM / 16, TJ = WN / 16;
    constexpr int ACHUNKS = BM * 4;            // 16B chunks per A k-tile
    constexpr int BCHUNKS = BN * 4;
    constexpr int AR = (ACHUNKS + 255) / 256;  // chunks per thread (ceil)
    constexpr int BR = (BCHUNKS + 255) / 256;
    __shared__ bf16 As[2][BM * LDA];
    __shared__ bf16 Bs[2][BN * LDA];
    const int tid = threadIdx.x;
    const int m0 = blockIdx.y * BM, n0 = blockIdx.x * BN;
    const int w = tid >> 6, lane = tid & 63;
    const int wm = (w >> 1) * WM, wn = (w & 1) * WN;
    const int li = lane & 15, quad = lane >> 4;

    floatx4 acc[TI][TJ] = {};
    float4 areg[AR], breg[BR];

    auto load_a = [&](int k0) {
#pragma unroll
        for (int i = 0; i < AR; i++) {
            int c = tid + i * 256;
            if (c < ACHUNKS) {
                int row = c >> 2, ko = (c & 3) << 3;
                int gm = m0 + row;
                areg[i] = make_float4(0.f, 0.f, 0.f, 0.f);
                if (gm < M) areg[i] = *(const float4*)(A + (size_t)gm * K + k0 + ko);
            }
        }
    };
    auto load_b = [&](int k0) {
#pragma unroll
        for (int i = 0; i < BR; i++) {
            int c = tid + i * 256;
            if (c < BCHUNKS) {
                int row = c >> 2, ko = (c & 3) << 3;
                breg[i] = *(const float4*)(W + (size_t)(n0 + row) * K + k0 + ko);
            }
        }
    };
    auto store_ab = [&](int buf) {
#pragma unroll
        for (int i = 0; i < AR; i++) {
            int c = tid + i * 256;
            if (c < ACHUNKS)
                *(float4*)&As[buf][(c >> 2) * LDA + ((c & 3) << 3)] = areg[i];
        }
#pragma unroll
        for (int i = 0; i < BR; i++) {
            int c = tid + i * 256;
            if (c < BCHUNKS)
                *(float4*)&Bs[buf][(c >> 2) * LDA + ((c & 3) << 3)] = breg[i];
        }
    };

    load_a(0);
    load_b(0);
    store_ab(0);
    __syncthreads();

    const int ktiles = K >> 5;
    for (int kt = 0; kt < ktiles; kt++) {
        const int cur = kt & 1;
        if (kt + 1 < ktiles) {
            load_a((kt + 1) << 5);
            load_b((kt + 1) << 5);
        }
        bf16x8 af[TI], bfr[TJ];
#pragma unroll
        for (int t = 0; t < TI; t++)
            af[t] = *(const bf16x8*)&As[cur][(wm + t * 16 + li) * LDA + quad * 8];
#pragma unroll
        for (int t = 0; t < TJ; t++)
            bfr[t] = *(const bf16x8*)&Bs[cur][(wn + t * 16 + li) * LDA + quad * 8];
#pragma unroll
        for (int ti = 0; ti < TI; ti++)
#pragma unroll
            for (int tj = 0; tj < TJ; tj++)
                acc[ti][tj] = __builtin_amdgcn_mfma_f32_16x16x32_bf16(
                    af[ti], bfr[tj], acc[ti][tj], 0, 0, 0);
        if (kt + 1 < ktiles) store_ab(cur ^ 1);
        __syncthreads();
    }

#pragma unroll
    for (int ti = 0; ti < TI; ti++) {
#pragma unroll
        for (int r = 0; r < 4; r++) {
            int gm = m0 + wm + ti * 16 + quad * 4 + r;
            if (gm >= M) continue;
#pragma unroll
            for (int tj = 0; tj < TJ; tj++) {
                int gn = n0 + wn + tj * 16 + li;
                float v = acc[ti][tj][r];
                if (bias) v += bias[gn];
                if (act == 1) v = 0.5f * v * (1.0f + erff(v * 0.70710678118654752f));
                if (posemb) v += posemb[(size_t)(gm % NTOK) * N + gn];
                if (resid) v += resid[(size_t)gm * N + gn];
                if (act == 2) {
                    // pix scatter: gm=(b,n), gn=(py,px) -> image (crop 464->457)
                    int b = gm / NTOK, n = gm - b * NTOK;
                    int hp = n / 29, wp = n - hp * 29;
                    int rr = hp * 16 + (gn >> 4), cc = wp * 16 + (gn & 15);
                    if (rr < IMG && cc < IMG)
                        Cf[((size_t)b * IMG + rr) * IMG + cc] = v;
                } else {
                    if (Cf) Cf[(size_t)gm * N + gn] = v;
                    if (Cb) Cb[(size_t)gm * N + gn] = __float2bfloat16(v);
                }
            }
        }
    }
}

// ---------------------------------------------------------------------------
// LayerNorm over last dim (256). One wave per row, 4 rows per block.
// ---------------------------------------------------------------------------
__global__ __launch_bounds__(256) void ln_kernel(const float* __restrict__ in,
                                                 const float* __restrict__ w,
                                                 const float* __restrict__ b,
                                                 bf16* __restrict__ out) {
    const int lane = threadIdx.x & 63;
    const int wv = threadIdx.x >> 6;
    const size_t row = (size_t)blockIdx.x * 4 + wv;
    const int c = lane * 4;
    float4 x = *(const float4*)&in[row * DIM + c];
    float s = x.x + x.y + x.z + x.w;
    float s2 = x.x * x.x + x.y * x.y + x.z * x.z + x.w * x.w;
#pragma unroll
    for (int off = 1; off < 64; off <<= 1) {
        s += __shfl_xor(s, off);
        s2 += __shfl_xor(s2, off);
    }
    float mean = s * (1.0f / DIM);
    float var = s2 * (1.0f / DIM) - mean * mean;
    float rstd = rsqrtf(var + 1e-5f);
    float4 w4 = *(const float4*)&w[c];
    float4 b4 = *(const float4*)&b[c];
    union { ushort4 u; bf16 h[4]; } pk;
    pk.h[0] = __float2bfloat16((x.x - mean) * rstd * w4.x + b4.x);
    pk.h[1] = __float2bfloat16((x.y - mean) * rstd * w4.y + b4.y);
    pk.h[2] = __float2bfloat16((x.z - mean) * rstd * w4.z + b4.z);
    pk.h[3] = __float2bfloat16((x.w - mean) * rstd * w4.w + b4.w);
    *(ushort4*)&out[row * DIM + c] = pk.u;
}

// ---------------------------------------------------------------------------
// MFMA flash attention (R10 proven), 256 threads, 1-barrier j-loop.
// qkv_b bf16 [b,n,768]. One block per (i-tile 64, b*8+h). Strict causal
// j < i; row 0 -> zeros. K/V double-buffered with register prefetch;
// Ps bands wave-local (no softmax->PV barrier).
// ---------------------------------------------------------------------------
#define LQ 40    // Qs/Ks row stride (bf16)
#define LP 72    // Ps/Vt row stride (bf16)
__global__ __launch_bounds__(256) void attn_mfma_kernel(
    const bf16* __restrict__ qkv, const float* __restrict__ scale,
    bf16* __restrict__ out) {
    __shared__ bf16 Qs[64 * LQ];        // [i][d]
    __shared__ bf16 Ks[2][64 * LQ];     // [j][d]
    __shared__ bf16 Vt[2][32 * LP];     // [d][j]
    __shared__ bf16 Ps[64 * LP];        // [i][j], wave-private row bands

    const int tid = threadIdx.x;
    const int bh = blockIdx.x;
    const int b = bh >> 3, h = bh & 7;
    const int it = (int)gridDim.y - 1 - (int)blockIdx.y;   // longest first
    const int i0 = it * 64;
    const float sc = scale[h];
    const bf16* base = qkv + (size_t)b * NTOK * 768 + h * DH;

    const int w = tid >> 6, lane = tid & 63;
    const int li = lane & 15, quad = lane >> 4;
    const int srow = tid >> 2, sd0 = (tid & 3) * 8;   // staging coords

    {
        int gi = i0 + srow;
        bf16x8 v = {};
        if (gi < NTOK) v = *(const bf16x8*)(base + (size_t)gi * 768 + sd0);
        *(bf16x8*)&Qs[srow * LQ + sd0] = v;
    }
    bf16x8 kreg = {}, vreg = {};
    {
        int gj = srow;
        if (gj < NTOK) {
            kreg = *(const bf16x8*)(base + (size_t)gj * 768 + 256 + sd0);
            vreg = *(const bf16x8*)(base + (size_t)gj * 768 + 512 + sd0);
        }
    }

    float m[4], l[4];
    floatx4 o[2] = {};
#pragma unroll
    for (int r = 0; r < 4; r++) { m[r] = -1e30f; l[r] = 0.0f; }

    for (int jt = 0; jt <= it; jt++) {
        const int j0 = jt * 64;
        const int cur = jt & 1;
        *(bf16x8*)&Ks[cur][srow * LQ + sd0] = kreg;
#pragma unroll
        for (int u = 0; u < 8; u++) Vt[cur][(sd0 + u) * LP + srow] = ((bf16*)&vreg)[u];
        if (jt < it) {
            int gj = j0 + 64 + srow;
            kreg = bf16x8{};
            vreg = bf16x8{};
            if (gj < NTOK) {
                kreg = *(const bf16x8*)(base + (size_t)gj * 768 + 256 + sd0);
                vreg = *(const bf16x8*)(base + (size_t)gj * 768 + 512 + sd0);
            }
        }
        __syncthreads();   // the only barrier per iteration

        bf16x8 aq = *(const bf16x8*)&Qs[(w * 16 + li) * LQ + quad * 8];
        floatx4 sacc[4];
#pragma unroll
        for (int tj = 0; tj < 4; tj++) {
            bf16x8 bk = *(const bf16x8*)&Ks[cur][(tj * 16 + li) * LQ + quad * 8];
            floatx4 z = {};
            sacc[tj] = __builtin_amdgcn_mfma_f32_16x16x32_bf16(aq, bk, z, 0, 0, 0);
        }

#pragma unroll
        for (int r = 0; r < 4; r++) {
            const int gi = i0 + w * 16 + quad * 4 + r;
            float sv[4], mloc = -1e30f;
#pragma unroll
            for (int tj = 0; tj < 4; tj++) {
                float v = sacc[tj][r] * sc;
                bool ok = (j0 + tj * 16 + li < gi) && (gi < NTOK);
                sv[tj] = ok ? v : -1e30f;
                mloc = fmaxf(mloc, sv[tj]);
            }
#pragma unroll
            for (int off = 1; off < 16; off <<= 1)
                mloc = fmaxf(mloc, __shfl_xor(mloc, off));
            float mnew = fmaxf(m[r], mloc);
            float alpha = __expf(m[r] - mnew);
            m[r] = mnew;
            float lsum = 0.0f;
#pragma unroll
            for (int tj = 0; tj < 4; tj++) {
                float p = __expf(sv[tj] - mnew);
                sv[tj] = p;
                lsum += p;
            }
#pragma unroll
            for (int off = 1; off < 16; off <<= 1)
                lsum += __shfl_xor(lsum, off);
            l[r] = l[r] * alpha + lsum;
            o[0][r] *= alpha;
            o[1][r] *= alpha;
#pragma unroll
            for (int tj = 0; tj < 4; tj++)
                Ps[(w * 16 + quad * 4 + r) * LP + tj * 16 + li] = __float2bfloat16(sv[tj]);
        }
        // no barrier: Ps rows [16w,16w+16) written and read by wave w only.

#pragma unroll
        for (int kk = 0; kk < 64; kk += 32) {
            bf16x8 ap = *(const bf16x8*)&Ps[(w * 16 + li) * LP + kk + quad * 8];
#pragma unroll
            for (int td = 0; td < 2; td++) {
                bf16x8 bv = *(const bf16x8*)&Vt[cur][(td * 16 + li) * LP + kk + quad * 8];
                o[td] = __builtin_amdgcn_mfma_f32_16x16x32_bf16(ap, bv, o[td], 0, 0, 0);
            }
        }
    }

#pragma unroll
    for (int r = 0; r < 4; r++) {
        int gi = i0 + w * 16 + quad * 4 + r;
        if (gi >= NTOK) continue;
        float iv = (gi > 0 && l[r] > 0.0f) ? 1.0f / l[r] : 0.0f;
        bf16* op = out + ((size_t)b * NTOK + gi) * DIM + h * DH;
        op[li]      = __float2bfloat16(o[0][r] * iv);
        op[16 + li] = __float2bfloat16(o[1][r] * iv);
    }
}

// ---------------------------------------------------------------------------
extern "C" void kernel_launch(void* const* d_in, const int* in_sizes, int n_in,
                              void* d_out, int out_size, void* d_ws, size_t ws_size,
                              hipStream_t stream) {
    const float* x     = (const float*)d_in[0];
    const float* pos   = (const float*)d_in[1];
    const float* sptw  = (const float*)d_in[2];
    const float* sptb  = (const float*)d_in[3];
    const float* ln1w  = (const float*)d_in[4];
    const float* ln1b  = (const float*)d_in[5];
    const float* scale = (const float*)d_in[6];
    const float* wqkv  = (const float*)d_in[7];
    const float* wout  = (const float*)d_in[8];
    const float* bout  = (const float*)d_in[9];
    const float* ln2w  = (const float*)d_in[10];
    const float* ln2b  = (const float*)d_in[11];
    const float* ff1w  = (const float*)d_in[12];
    const float* ff1b  = (const float*)d_in[13];
    const float* ff2w  = (const float*)d_in[14];
    const float* ff2b  = (const float*)d_in[15];
    const float* pixw  = (const float*)d_in[16];
    const float* pixb  = (const float*)d_in[17];
    float* out = (float*)d_out;

    const size_t NT = (size_t)ROWS * DIM;
    char* ws = (char*)d_ws;
    float* t    = (float*)ws;                         ws += NT * 4;
    bf16*  tn_b = (bf16*)ws;                          ws += NT * 2;
    bf16*  t_b  = (bf16*)ws;                          ws += NT * 2;
    bf16*  ao_b = (bf16*)ws;                          ws += NT * 2;
    bf16*  wbf  = (bf16*)ws;                          ws += (size_t)W_TOTAL * 2;
    char*  big  = ws;                                  // time-shared region
    bf16*  tok   = (bf16*)big;
    bf16*  qkv_b = (bf16*)big;
    bf16*  ffh   = (bf16*)big;

    wconv_kernel<<<W_TOTAL / 4 / 256, 256, 0, stream>>>(sptw, wqkv, wout, ff1w,
                                                        ff2w, pixw, wbf);
    tokenize_kernel<<<(ROWS * 320) / 256, 256, 0, stream>>>(x, tok);
    // SPT projection + bias + pos_emb -> t (fp32). 32x64 tiles: 844 blocks.
    gemm_db_kernel<32, 64><<<dim3(4, 211), 256, 0, stream>>>(
        tok, wbf + W_SPT, sptb, nullptr, pos, t, nullptr, ROWS, DIM, 1280, 0);

    for (int d = 0; d < 3; d++) {
        ln_kernel<<<ROWS / 4, 256, 0, stream>>>(t, ln1w + d * DIM, ln1b + d * DIM, tn_b);
        // QKV -> bf16 (64x64: 1272 blocks)
        gemm_db_kernel<64, 64><<<dim3(12, 106), 256, 0, stream>>>(
            tn_b, wbf + W_QKV + (size_t)d * 768 * DIM, nullptr, nullptr, nullptr,
            nullptr, qkv_b, ROWS, 768, DIM, 0);
        // MFMA flash attention -> bf16
        {
            dim3 grid(BATCH * HEADS, (NTOK + 63) / 64);   // (64, 14)
            attn_mfma_kernel<<<grid, 256, 0, stream>>>(qkv_b, scale + d * HEADS, ao_b);
        }
        // out proj + bias + residual -> t (32x64: 844 blocks)
        gemm_db_kernel<32, 64><<<dim3(4, 211), 256, 0, stream>>>(
            ao_b, wbf + W_OUT + (size_t)d * DIM * DIM, bout + d * DIM, t, nullptr,
            t, nullptr, ROWS, DIM, DIM, 0);
        ln_kernel<<<ROWS / 4, 256, 0, stream>>>(t, ln2w + d * DIM, ln2b + d * DIM, tn_b);
        // FF1 + gelu -> bf16 (64x64: 1696 blocks)
        gemm_db_kernel<64, 64><<<dim3(16, 106), 256, 0, stream>>>(
            tn_b, wbf + W_FF1 + (size_t)d * 1024 * DIM, ff1b + d * 1024, nullptr,
            nullptr, nullptr, ffh, ROWS, 1024, DIM, 1);
        // FF2 + bias + residual -> t (fp32) and t_b (bf16) (32x64: 844 blocks)
        gemm_db_kernel<32, 64><<<dim3(4, 211), 256, 0, stream>>>(
            ffh, wbf + W_FF2 + (size_t)d * DIM * 1024, ff2b + d * DIM, t, nullptr,
            t, t_b, ROWS, DIM, 1024, 0);
    }

    // pix projection with fused scatter -> out image (act=2, 32x64: 844 blocks)
    gemm_db_kernel<32, 64><<<dim3(4, 211), 256, 0, stream>>>(
        t_b, wbf + W_PIX, pixb, nullptr, nullptr, out, nullptr, ROWS, DIM, DIM, 2);
}

// Round 18
// 447.178 us; speedup vs baseline: 1.0109x; 1.0109x over previous
//
#include <hip/hip_runtime.h>
#include <hip/hip_bf16.h>
#include <math.h>

typedef __hip_bfloat16 bf16;
typedef short bf16x8 __attribute__((ext_vector_type(8)));
typedef float floatx4 __attribute__((ext_vector_type(4)));

#define NTOK 841          // 29*29 patches
#define BATCH 8
#define DIM 256
#define HEADS 8
#define DH 32
#define IMG 457
#define HPAD 464
#define ROWS (BATCH * NTOK)   // 6728
#define LDA 40                // padded LDS row stride (bf16 elems) -> 80B

// weight segment offsets (elements) in the packed bf16 weight buffer
#define W_SPT   0
#define W_QKV   327680
#define W_OUT   917504
#define W_FF1   1114112
#define W_FF2   1900544
#define W_PIX   2686976
#define W_TOTAL 2752512

// ---------------------------------------------------------------------------
// Convert all weight tensors fp32 -> bf16 into one packed buffer.
// ---------------------------------------------------------------------------
__global__ __launch_bounds__(256) void wconv_kernel(
    const float* __restrict__ s_spt, const float* __restrict__ s_qkv,
    const float* __restrict__ s_out, const float* __restrict__ s_ff1,
    const float* __restrict__ s_ff2, const float* __restrict__ s_pix,
    bf16* __restrict__ dst) {
    int idx = (blockIdx.x * 256 + threadIdx.x) * 4;
    const float* src; int off;
    if      (idx < W_QKV) { src = s_spt; off = W_SPT; }
    else if (idx < W_OUT) { src = s_qkv; off = W_QKV; }
    else if (idx < W_FF1) { src = s_out; off = W_OUT; }
    else if (idx < W_FF2) { src = s_ff1; off = W_FF1; }
    else if (idx < W_PIX) { src = s_ff2; off = W_FF2; }
    else                  { src = s_pix; off = W_PIX; }
    float4 v = *(const float4*)(src + (idx - off));
    union { ushort4 u; bf16 h[4]; } pk;
    pk.h[0] = __float2bfloat16(v.x);
    pk.h[1] = __float2bfloat16(v.y);
    pk.h[2] = __float2bfloat16(v.z);
    pk.h[3] = __float2bfloat16(v.w);
    *(ushort4*)(dst + idx) = pk.u;
}

// ---------------------------------------------------------------------------
// Tokenize gather -> bf16 tok[ROWS][1280], k=(c,py,px).  (R6 proven)
// ---------------------------------------------------------------------------
__global__ __launch_bounds__(256) void tokenize_kernel(const float* __restrict__ x,
                                                       bf16* __restrict__ tok) {
    int idx = blockIdx.x * 256 + threadIdx.x;
    int gm = idx / 320;
    int k4 = (idx - gm * 320) * 4;
    int b = gm / NTOK;
    int n = gm - b * NTOK;
    int hp = n / 29, wp = n - (n / 29) * 29;
    int c = k4 >> 8;
    int py = (k4 >> 4) & 15;
    int px0 = k4 & 15;
    const int dxs[5] = {0, -8, 8, -8, 8};
    const int dys[5] = {0, -8, -8, 8, 8};
    int r = hp * 16 + py - dys[c];
    r += (r < 0) ? HPAD : 0; r -= (r >= HPAD) ? HPAD : 0;
    bool rok = (r < IMG);
    union { ushort4 u; bf16 h[4]; } pk;
#pragma unroll
    for (int i = 0; i < 4; i++) {
        int s = wp * 16 + px0 + i - dxs[c];
        s += (s < 0) ? HPAD : 0; s -= (s >= HPAD) ? HPAD : 0;
        float v = 0.0f;
        if (rok && s < IMG) v = x[((size_t)b * IMG + r) * IMG + s];
        pk.h[i] = __float2bfloat16(v);
    }
    *(ushort4*)(tok + (size_t)gm * 1280 + k4) = pk.u;
}

// ---------------------------------------------------------------------------
// Double-buffered MFMA GEMM (R16 proven): C = A@W^T, BK=32, 4 waves (2x2).
// Supports BM=32 (guarded staging). act: 0 none, 1 gelu.
// NOTE (R14): BM=32 only for N=256 GEMMs; wide-N GEMMs use BM=64 and gain
// grid occupancy by shrinking BN (R16: 64x64 QKV/FF1 = -81 us).
// NOTE (R17): pix-scatter fused epilogue measured neutral-to-negative —
// keep the dedicated scatter kernel.
// ---------------------------------------------------------------------------
template <int BM, int BN>
__global__ __launch_bounds__(256) void gemm_db_kernel(
    const bf16* __restrict__ A, const bf16* __restrict__ W,
    const float* __restrict__ bias, const float* __restrict__ resid,
    const float* __restrict__ posemb, float* __restrict__ Cf,
    bf16* __restrict__ Cb, int M, int N, int K, int act) {
    constexpr int WM = BM / 2, WN = BN / 2;
    constexpr int TI = WM / 16, TJ = WN / 16;
    constexpr int ACHUNKS = BM * 4;            // 16B chunks per A k-tile
    constexpr int BCHUNKS = BN * 4;
    constexpr int AR = (ACHUNKS + 255) / 256;  // chunks per thread (ceil)
    constexpr int BR = (BCHUNKS + 255) / 256;
    __shared__ bf16 As[2][BM * LDA];
    __shared__ bf16 Bs[2][BN * LDA];
    const int tid = threadIdx.x;
    const int m0 = blockIdx.y * BM, n0 = blockIdx.x * BN;
    const int w = tid >> 6, lane = tid & 63;
    const int wm = (w >> 1) * WM, wn = (w & 1) * WN;
    const int li = lane & 15, quad = lane >> 4;

    floatx4 acc[TI][TJ] = {};
    float4 areg[AR], breg[BR];

    auto load_a = [&](int k0) {
#pragma unroll
        for (int i = 0; i < AR; i++) {
            int c = tid + i * 256;
            if (c < ACHUNKS) {
                int row = c >> 2, ko = (c & 3) << 3;
                int gm = m0 + row;
                areg[i] = make_float4(0.f, 0.f, 0.f, 0.f);
                if (gm < M) areg[i] = *(const float4*)(A + (size_t)gm * K + k0 + ko);
            }
        }
    };
    auto load_b = [&](int k0) {
#pragma unroll
        for (int i = 0; i < BR; i++) {
            int c = tid + i * 256;
            if (c < BCHUNKS) {
                int row = c >> 2, ko = (c & 3) << 3;
                breg[i] = *(const float4*)(W + (size_t)(n0 + row) * K + k0 + ko);
            }
        }
    };
    auto store_ab = [&](int buf) {
#pragma unroll
        for (int i = 0; i < AR; i++) {
            int c = tid + i * 256;
            if (c < ACHUNKS)
                *(float4*)&As[buf][(c >> 2) * LDA + ((c & 3) << 3)] = areg[i];
        }
#pragma unroll
        for (int i = 0; i < BR; i++) {
            int c = tid + i * 256;
            if (c < BCHUNKS)
                *(float4*)&Bs[buf][(c >> 2) * LDA + ((c & 3) << 3)] = breg[i];
        }
    };

    load_a(0);
    load_b(0);
    store_ab(0);
    __syncthreads();

    const int ktiles = K >> 5;
    for (int kt = 0; kt < ktiles; kt++) {
        const int cur = kt & 1;
        if (kt + 1 < ktiles) {
            load_a((kt + 1) << 5);
            load_b((kt + 1) << 5);
        }
        bf16x8 af[TI], bfr[TJ];
#pragma unroll
        for (int t = 0; t < TI; t++)
            af[t] = *(const bf16x8*)&As[cur][(wm + t * 16 + li) * LDA + quad * 8];
#pragma unroll
        for (int t = 0; t < TJ; t++)
            bfr[t] = *(const bf16x8*)&Bs[cur][(wn + t * 16 + li) * LDA + quad * 8];
#pragma unroll
        for (int ti = 0; ti < TI; ti++)
#pragma unroll
            for (int tj = 0; tj < TJ; tj++)
                acc[ti][tj] = __builtin_amdgcn_mfma_f32_16x16x32_bf16(
                    af[ti], bfr[tj], acc[ti][tj], 0, 0, 0);
        if (kt + 1 < ktiles) store_ab(cur ^ 1);
        __syncthreads();
    }

#pragma unroll
    for (int ti = 0; ti < TI; ti++) {
#pragma unroll
        for (int r = 0; r < 4; r++) {
            int gm = m0 + wm + ti * 16 + quad * 4 + r;
            if (gm >= M) continue;
#pragma unroll
            for (int tj = 0; tj < TJ; tj++) {
                int gn = n0 + wn + tj * 16 + li;
                float v = acc[ti][tj][r];
                if (bias) v += bias[gn];
                if (act == 1) v = 0.5f * v * (1.0f + erff(v * 0.70710678118654752f));
                if (posemb) v += posemb[(size_t)(gm % NTOK) * N + gn];
                if (resid) v += resid[(size_t)gm * N + gn];
                if (Cf) Cf[(size_t)gm * N + gn] = v;
                if (Cb) Cb[(size_t)gm * N + gn] = __float2bfloat16(v);
            }
        }
    }
}

// ---------------------------------------------------------------------------
// LayerNorm over last dim (256). One wave per row, 4 rows per block.
// ---------------------------------------------------------------------------
__global__ __launch_bounds__(256) void ln_kernel(const float* __restrict__ in,
                                                 const float* __restrict__ w,
                                                 const float* __restrict__ b,
                                                 bf16* __restrict__ out) {
    const int lane = threadIdx.x & 63;
    const int wv = threadIdx.x >> 6;
    const size_t row = (size_t)blockIdx.x * 4 + wv;
    const int c = lane * 4;
    float4 x = *(const float4*)&in[row * DIM + c];
    float s = x.x + x.y + x.z + x.w;
    float s2 = x.x * x.x + x.y * x.y + x.z * x.z + x.w * x.w;
#pragma unroll
    for (int off = 1; off < 64; off <<= 1) {
        s += __shfl_xor(s, off);
        s2 += __shfl_xor(s2, off);
    }
    float mean = s * (1.0f / DIM);
    float var = s2 * (1.0f / DIM) - mean * mean;
    float rstd = rsqrtf(var + 1e-5f);
    float4 w4 = *(const float4*)&w[c];
    float4 b4 = *(const float4*)&b[c];
    union { ushort4 u; bf16 h[4]; } pk;
    pk.h[0] = __float2bfloat16((x.x - mean) * rstd * w4.x + b4.x);
    pk.h[1] = __float2bfloat16((x.y - mean) * rstd * w4.y + b4.y);
    pk.h[2] = __float2bfloat16((x.z - mean) * rstd * w4.z + b4.z);
    pk.h[3] = __float2bfloat16((x.w - mean) * rstd * w4.w + b4.w);
    *(ushort4*)&out[row * DIM + c] = pk.u;
}

// ---------------------------------------------------------------------------
// MFMA flash attention (R10 proven), 256 threads, 1-barrier j-loop.
// qkv_b bf16 [b,n,768]. One block per (i-tile 64, b*8+h). Strict causal
// j < i; row 0 -> zeros. K/V double-buffered with register prefetch;
// Ps bands wave-local (no softmax->PV barrier).
// ---------------------------------------------------------------------------
#define LQ 40    // Qs/Ks row stride (bf16)
#define LP 72    // Ps/Vt row stride (bf16)
__global__ __launch_bounds__(256) void attn_mfma_kernel(
    const bf16* __restrict__ qkv, const float* __restrict__ scale,
    bf16* __restrict__ out) {
    __shared__ bf16 Qs[64 * LQ];        // [i][d]
    __shared__ bf16 Ks[2][64 * LQ];     // [j][d]
    __shared__ bf16 Vt[2][32 * LP];     // [d][j]
    __shared__ bf16 Ps[64 * LP];        // [i][j], wave-private row bands

    const int tid = threadIdx.x;
    const int bh = blockIdx.x;
    const int b = bh >> 3, h = bh & 7;
    const int it = (int)gridDim.y - 1 - (int)blockIdx.y;   // longest first
    const int i0 = it * 64;
    const float sc = scale[h];
    const bf16* base = qkv + (size_t)b * NTOK * 768 + h * DH;

    const int w = tid >> 6, lane = tid & 63;
    const int li = lane & 15, quad = lane >> 4;
    const int srow = tid >> 2, sd0 = (tid & 3) * 8;   // staging coords

    {
        int gi = i0 + srow;
        bf16x8 v = {};
        if (gi < NTOK) v = *(const bf16x8*)(base + (size_t)gi * 768 + sd0);
        *(bf16x8*)&Qs[srow * LQ + sd0] = v;
    }
    bf16x8 kreg = {}, vreg = {};
    {
        int gj = srow;
        if (gj < NTOK) {
            kreg = *(const bf16x8*)(base + (size_t)gj * 768 + 256 + sd0);
            vreg = *(const bf16x8*)(base + (size_t)gj * 768 + 512 + sd0);
        }
    }

    float m[4], l[4];
    floatx4 o[2] = {};
#pragma unroll
    for (int r = 0; r < 4; r++) { m[r] = -1e30f; l[r] = 0.0f; }

    for (int jt = 0; jt <= it; jt++) {
        const int j0 = jt * 64;
        const int cur = jt & 1;
        *(bf16x8*)&Ks[cur][srow * LQ + sd0] = kreg;
#pragma unroll
        for (int u = 0; u < 8; u++) Vt[cur][(sd0 + u) * LP + srow] = ((bf16*)&vreg)[u];
        if (jt < it) {
            int gj = j0 + 64 + srow;
            kreg = bf16x8{};
            vreg = bf16x8{};
            if (gj < NTOK) {
                kreg = *(const bf16x8*)(base + (size_t)gj * 768 + 256 + sd0);
                vreg = *(const bf16x8*)(base + (size_t)gj * 768 + 512 + sd0);
            }
        }
        __syncthreads();   // the only barrier per iteration

        bf16x8 aq = *(const bf16x8*)&Qs[(w * 16 + li) * LQ + quad * 8];
        floatx4 sacc[4];
#pragma unroll
        for (int tj = 0; tj < 4; tj++) {
            bf16x8 bk = *(const bf16x8*)&Ks[cur][(tj * 16 + li) * LQ + quad * 8];
            floatx4 z = {};
            sacc[tj] = __builtin_amdgcn_mfma_f32_16x16x32_bf16(aq, bk, z, 0, 0, 0);
        }

#pragma unroll
        for (int r = 0; r < 4; r++) {
            const int gi = i0 + w * 16 + quad * 4 + r;
            float sv[4], mloc = -1e30f;
#pragma unroll
            for (int tj = 0; tj < 4; tj++) {
                float v = sacc[tj][r] * sc;
                bool ok = (j0 + tj * 16 + li < gi) && (gi < NTOK);
                sv[tj] = ok ? v : -1e30f;
                mloc = fmaxf(mloc, sv[tj]);
            }
#pragma unroll
            for (int off = 1; off < 16; off <<= 1)
                mloc = fmaxf(mloc, __shfl_xor(mloc, off));
            float mnew = fmaxf(m[r], mloc);
            float alpha = __expf(m[r] - mnew);
            m[r] = mnew;
            float lsum = 0.0f;
#pragma unroll
            for (int tj = 0; tj < 4; tj++) {
                float p = __expf(sv[tj] - mnew);
                sv[tj] = p;
                lsum += p;
            }
#pragma unroll
            for (int off = 1; off < 16; off <<= 1)
                lsum += __shfl_xor(lsum, off);
            l[r] = l[r] * alpha + lsum;
            o[0][r] *= alpha;
            o[1][r] *= alpha;
#pragma unroll
            for (int tj = 0; tj < 4; tj++)
                Ps[(w * 16 + quad * 4 + r) * LP + tj * 16 + li] = __float2bfloat16(sv[tj]);
        }
        // no barrier: Ps rows [16w,16w+16) written and read by wave w only.

#pragma unroll
        for (int kk = 0; kk < 64; kk += 32) {
            bf16x8 ap = *(const bf16x8*)&Ps[(w * 16 + li) * LP + kk + quad * 8];
#pragma unroll
            for (int td = 0; td < 2; td++) {
                bf16x8 bv = *(const bf16x8*)&Vt[cur][(td * 16 + li) * LP + kk + quad * 8];
                o[td] = __builtin_amdgcn_mfma_f32_16x16x32_bf16(ap, bv, o[td], 0, 0, 0);
            }
        }
    }

#pragma unroll
    for (int r = 0; r < 4; r++) {
        int gi = i0 + w * 16 + quad * 4 + r;
        if (gi >= NTOK) continue;
        float iv = (gi > 0 && l[r] > 0.0f) ? 1.0f / l[r] : 0.0f;
        bf16* op = out + ((size_t)b * NTOK + gi) * DIM + h * DH;
        op[li]      = __float2bfloat16(o[0][r] * iv);
        op[16 + li] = __float2bfloat16(o[1][r] * iv);
    }
}

// ---------------------------------------------------------------------------
// Scatter pix [B, N, 256] fp32 -> out image [B,1,457,457] fp32 (crop)
// ---------------------------------------------------------------------------
__global__ __launch_bounds__(256) void scatter_kernel(const float* __restrict__ pix,
                                                      float* __restrict__ out) {
    const size_t total = (size_t)BATCH * IMG * IMG;
    size_t idx = (size_t)blockIdx.x * 256 + threadIdx.x;
    if (idx >= total) return;
    int b = (int)(idx / ((size_t)IMG * IMG));
    int rem = (int)(idx % ((size_t)IMG * IMG));
    int r = rem / IMG, col = rem % IMG;
    int hp = r >> 4, py = r & 15;
    int wp = col >> 4, px = col & 15;
    out[idx] = pix[((size_t)b * NTOK + hp * 29 + wp) * DIM + py * 16 + px];
}

// ---------------------------------------------------------------------------
extern "C" void kernel_launch(void* const* d_in, const int* in_sizes, int n_in,
                              void* d_out, int out_size, void* d_ws, size_t ws_size,
                              hipStream_t stream) {
    const float* x     = (const float*)d_in[0];
    const float* pos   = (const float*)d_in[1];
    const float* sptw  = (const float*)d_in[2];
    const float* sptb  = (const float*)d_in[3];
    const float* ln1w  = (const float*)d_in[4];
    const float* ln1b  = (const float*)d_in[5];
    const float* scale = (const float*)d_in[6];
    const float* wqkv  = (const float*)d_in[7];
    const float* wout  = (const float*)d_in[8];
    const float* bout  = (const float*)d_in[9];
    const float* ln2w  = (const float*)d_in[10];
    const float* ln2b  = (const float*)d_in[11];
    const float* ff1w  = (const float*)d_in[12];
    const float* ff1b  = (const float*)d_in[13];
    const float* ff2w  = (const float*)d_in[14];
    const float* ff2b  = (const float*)d_in[15];
    const float* pixw  = (const float*)d_in[16];
    const float* pixb  = (const float*)d_in[17];
    float* out = (float*)d_out;

    const size_t NT = (size_t)ROWS * DIM;
    char* ws = (char*)d_ws;
    float* t    = (float*)ws;                         ws += NT * 4;
    bf16*  tn_b = (bf16*)ws;                          ws += NT * 2;
    bf16*  t_b  = (bf16*)ws;                          ws += NT * 2;
    bf16*  ao_b = (bf16*)ws;                          ws += NT * 2;
    bf16*  wbf  = (bf16*)ws;                          ws += (size_t)W_TOTAL * 2;
    char*  big  = ws;                                  // time-shared region
    bf16*  tok   = (bf16*)big;
    bf16*  qkv_b = (bf16*)big;
    bf16*  ffh   = (bf16*)big;
    float* pixo  = (float*)big;

    wconv_kernel<<<W_TOTAL / 4 / 256, 256, 0, stream>>>(sptw, wqkv, wout, ff1w,
                                                        ff2w, pixw, wbf);
    tokenize_kernel<<<(ROWS * 320) / 256, 256, 0, stream>>>(x, tok);
    // SPT projection + bias + pos_emb -> t (fp32). 32x64 tiles: 844 blocks.
    gemm_db_kernel<32, 64><<<dim3(4, 211), 256, 0, stream>>>(
        tok, wbf + W_SPT, sptb, nullptr, pos, t, nullptr, ROWS, DIM, 1280, 0);

    for (int d = 0; d < 3; d++) {
        ln_kernel<<<ROWS / 4, 256, 0, stream>>>(t, ln1w + d * DIM, ln1b + d * DIM, tn_b);
        // QKV -> bf16 (64x64: 1272 blocks)
        gemm_db_kernel<64, 64><<<dim3(12, 106), 256, 0, stream>>>(
            tn_b, wbf + W_QKV + (size_t)d * 768 * DIM, nullptr, nullptr, nullptr,
            nullptr, qkv_b, ROWS, 768, DIM, 0);
        // MFMA flash attention -> bf16
        {
            dim3 grid(BATCH * HEADS, (NTOK + 63) / 64);   // (64, 14)
            attn_mfma_kernel<<<grid, 256, 0, stream>>>(qkv_b, scale + d * HEADS, ao_b);
        }
        // out proj + bias + residual -> t (32x64: 844 blocks)
        gemm_db_kernel<32, 64><<<dim3(4, 211), 256, 0, stream>>>(
            ao_b, wbf + W_OUT + (size_t)d * DIM * DIM, bout + d * DIM, t, nullptr,
            t, nullptr, ROWS, DIM, DIM, 0);
        ln_kernel<<<ROWS / 4, 256, 0, stream>>>(t, ln2w + d * DIM, ln2b + d * DIM, tn_b);
        // FF1 + gelu -> bf16 (64x64: 1696 blocks)
        gemm_db_kernel<64, 64><<<dim3(16, 106), 256, 0, stream>>>(
            tn_b, wbf + W_FF1 + (size_t)d * 1024 * DIM, ff1b + d * 1024, nullptr,
            nullptr, nullptr, ffh, ROWS, 1024, DIM, 1);
        // FF2 + bias + residual -> t (fp32) and t_b (bf16) (32x64: 844 blocks)
        gemm_db_kernel<32, 64><<<dim3(4, 211), 256, 0, stream>>>(
            ffh, wbf + W_FF2 + (size_t)d * DIM * 1024, ff2b + d * DIM, t, nullptr,
            t, t_b, ROWS, DIM, 1024, 0);
    }

    // pix projection -> pixo (fp32), then scatter to output image
    gemm_db_kernel<32, 64><<<dim3(4, 211), 256, 0, stream>>>(
        t_b, wbf + W_PIX, pixb, nullptr, nullptr, pixo, nullptr, ROWS, DIM, DIM, 0);
    {
        size_t total = (size_t)BATCH * IMG * IMG;
        scatter_kernel<<<dim3((unsigned)((total + 255) / 256)), 256, 0, stream>>>(pixo, out);
    }
}